// Round 1
// baseline (433.435 us; speedup 1.0000x reference)
//
#include <hip/hip_runtime.h>
#include <hip/hip_bf16.h>

typedef __bf16 bf16;
typedef __bf16 bf16x4 __attribute__((ext_vector_type(4)));
typedef __bf16 bf16x8 __attribute__((ext_vector_type(8)));
typedef float floatx4 __attribute__((ext_vector_type(4)));

#define EMBED 1024
#define VOCAB 32000
#define BB    4
#define SS    4096
#define NTOK  (BB * SS)   // 16384
#define NKV   2048        // K and V concatenated

// ---- async global->LDS, 16B per lane (lane-contiguous LDS dest required) ----
__device__ __forceinline__ void async_copy16(void* lds, const void* g) {
    __builtin_amdgcn_global_load_lds(
        (const __attribute__((address_space(1))) unsigned int*)g,
        (__attribute__((address_space(3))) unsigned int*)lds, 16, 0, 0);
}

// ============================================================================
// K1: gather h = embed[x] -> bf16 (A matrix of the KV GEMM); also stash the
// last token per batch in fp32 (residual + Q input) and init h_final with it.
// ============================================================================
__global__ void gather_embed(const int* __restrict__ x,
                             const float* __restrict__ embed,
                             bf16* __restrict__ h,
                             float* __restrict__ h_last,
                             float* __restrict__ h_final) {
    int t = blockIdx.x;            // 16384 tokens
    int tid = threadIdx.x;         // 256
    int row = x[t];                // broadcast scalar load
    const float4* src = (const float4*)(embed + (size_t)row * EMBED);
    float4 v = src[tid];           // 256*4 = 1024 floats
    bf16x4 o; o.x = (bf16)v.x; o.y = (bf16)v.y; o.z = (bf16)v.z; o.w = (bf16)v.w;
    *(bf16x4*)(h + (size_t)t * EMBED + tid * 4) = o;
    if ((t & (SS - 1)) == SS - 1) {
        int b = t >> 12;
        *(float4*)(h_last  + b * EMBED + tid * 4) = v;
        *(float4*)(h_final + b * EMBED + tid * 4) = v;   // residual init
    }
}

// ============================================================================
// K2: init q (= qkv_b[0:1024] per batch) and out (= out_b per batch);
// they are accumulated into via atomics later. (ws/out are poisoned 0xAA.)
// ============================================================================
__global__ void init_qout(const float* __restrict__ qkv_b,
                          const float* __restrict__ out_b,
                          float* __restrict__ q, float* __restrict__ out) {
    int i = blockIdx.x * 256 + threadIdx.x;
    if (i < BB * VOCAB) {
        out[i] = out_b[i % VOCAB];
    } else if (i < BB * VOCAB + BB * EMBED) {
        int k = i - BB * VOCAB;
        q[k] = qkv_b[k & (EMBED - 1)];
    }
}

// ============================================================================
// K3: transpose+convert qkv_w[:, 1024:3072] (fp32, row-major d x 3072) into
// WkvT[n][d] bf16 (2048 x 1024) so GEMM B staging matches A staging (B^T).
// ============================================================================
__global__ void wkvt_transpose(const float* __restrict__ qkv_w,
                               bf16* __restrict__ WkvT) {
    __shared__ float T[32][33];                 // +1 pad: conflict-free
    int n0 = blockIdx.x * 32, d0 = blockIdx.y * 32;
    int tid = threadIdx.x;
    int c = tid & 31, r = tid >> 5;             // r: 0..7
#pragma unroll
    for (int i = 0; i < 4; ++i) {
        int d = r + i * 8;
        T[c][d] = qkv_w[(size_t)(d0 + d) * (3 * EMBED) + EMBED + n0 + c];
    }
    __syncthreads();
#pragma unroll
    for (int i = 0; i < 4; ++i) {
        int n = r + i * 8;
        WkvT[(size_t)(n0 + n) * EMBED + d0 + c] = (bf16)T[n][c];
    }
}

// ============================================================================
// K4: q = h_last @ qkv_w[:, 0:1024]  (fp32, tiny: 4x1024 @ 1024x1024)
// grid: x = j-chunk (4 x 256 cols), y = d-segment (4 x 256), atomicAdd into q.
// ============================================================================
__global__ void q_gemm(const float* __restrict__ h_last,
                       const float* __restrict__ qkv_w,
                       float* __restrict__ q) {
    __shared__ float hs[BB * 256];
    int tid = threadIdx.x;
    int j = blockIdx.x * 256 + tid;             // 0..1023
    int d0 = blockIdx.y * 256;
    for (int i = tid; i < BB * 256; i += 256)
        hs[i] = h_last[(i >> 8) * EMBED + d0 + (i & 255)];
    __syncthreads();
    float a0 = 0, a1 = 0, a2 = 0, a3 = 0;
#pragma unroll 4
    for (int dd = 0; dd < 256; ++dd) {
        float wv = qkv_w[(size_t)(d0 + dd) * (3 * EMBED) + j];
        a0 += hs[dd] * wv; a1 += hs[256 + dd] * wv;
        a2 += hs[512 + dd] * wv; a3 += hs[768 + dd] * wv;
    }
    atomicAdd(q + j, a0);
    atomicAdd(q + EMBED + j, a1);
    atomicAdd(q + 2 * EMBED + j, a2);
    atomicAdd(q + 3 * EMBED + j, a3);
}

// ============================================================================
// K5: the big GEMM. KV[16384 x 2048] = h[16384 x 1024] @ WkvT^T + bias, bf16
// MFMA 16x16x32, 128x128 block tile, BK=32, global_load_lds width-16 staging.
// ============================================================================
__global__ __launch_bounds__(256, 2) void gemm_kv(
    const bf16* __restrict__ A,    // 16384 x 1024 row-major
    const bf16* __restrict__ BT,   // 2048 x 1024 (B transposed, row-major)
    const float* __restrict__ bias,// 2048 (qkv_b + 1024)
    bf16* __restrict__ C) {        // 16384 x 2048
    __shared__ bf16 As[128 * 32];
    __shared__ bf16 Bs[128 * 32];
    const int K = EMBED;
    int tid = threadIdx.x;
    int wave = tid >> 6, lane = tid & 63;
    int wm = wave >> 1, wn = wave & 1;          // 2x2 waves of 64x64
    int quad = lane >> 4, l16 = lane & 15;

    floatx4 acc[4][4];
#pragma unroll
    for (int a = 0; a < 4; ++a)
#pragma unroll
        for (int b = 0; b < 4; ++b) acc[a][b] = (floatx4)0.0f;

    const bf16* Abase = A + (size_t)blockIdx.x * 128 * K;
    const bf16* Bbase = BT + (size_t)blockIdx.y * 128 * K;

    for (int k0 = 0; k0 < K; k0 += 32) {
        __syncthreads();   // previous iter's readers done before overwrite
#pragma unroll
        for (int i = 0; i < 2; ++i) {
            int c = wave * 128 + i * 64 + lane;     // 0..511; LDS dest lane-contig
            int row = c >> 2, ko = (c & 3) * 8;
            async_copy16(As + c * 8, Abase + (size_t)row * K + k0 + ko);
            async_copy16(Bs + c * 8, Bbase + (size_t)row * K + k0 + ko);
        }
        __syncthreads();   // emits s_waitcnt vmcnt(0) before barrier
        bf16x8 af[4], bfr[4];
#pragma unroll
        for (int mt = 0; mt < 4; ++mt)
            af[mt] = *(const bf16x8*)(As + (wm * 64 + mt * 16 + l16) * 32 + quad * 8);
#pragma unroll
        for (int nt = 0; nt < 4; ++nt)
            bfr[nt] = *(const bf16x8*)(Bs + (wn * 64 + nt * 16 + l16) * 32 + quad * 8);
#pragma unroll
        for (int mt = 0; mt < 4; ++mt)
#pragma unroll
            for (int nt = 0; nt < 4; ++nt)
                acc[mt][nt] = __builtin_amdgcn_mfma_f32_16x16x32_bf16(
                    af[mt], bfr[nt], acc[mt][nt], 0, 0, 0);
    }

    // epilogue: C/D layout col = lane&15, row = quad*4 + reg
    int crow0 = blockIdx.x * 128 + wm * 64;
    int ccol0 = blockIdx.y * 128 + wn * 64;
#pragma unroll
    for (int mt = 0; mt < 4; ++mt)
#pragma unroll
        for (int nt = 0; nt < 4; ++nt) {
            int col = ccol0 + nt * 16 + l16;
            float bs = bias[col];
#pragma unroll
            for (int r = 0; r < 4; ++r) {
                int row = crow0 + mt * 16 + quad * 4 + r;
                C[(size_t)row * NKV + col] = (bf16)(acc[mt][nt][r] + bs);
            }
        }
}

// ============================================================================
// K6: logits[b][t] = (q[b] . K[b,t]) / 32   — one wave per (b,t)
// ============================================================================
__global__ void attn_logits(const bf16* __restrict__ KV,
                            const float* __restrict__ q,
                            float* __restrict__ logits) {
    int gw = blockIdx.x * 4 + (threadIdx.x >> 6);   // 0..16383
    int b = gw >> 12, t = gw & (SS - 1);
    int lane = threadIdx.x & 63;
    const bf16* Krow = KV + (size_t)(b * SS + t) * NKV;   // K in cols [0,1024)
    const float* qb = q + b * EMBED;
    float sum = 0.0f;
#pragma unroll
    for (int i = 0; i < 2; ++i) {
        int d0 = i * 512 + lane * 8;
        bf16x8 kv8 = *(const bf16x8*)(Krow + d0);
        float4 qa = *(const float4*)(qb + d0);
        float4 qc = *(const float4*)(qb + d0 + 4);
        sum += qa.x * (float)kv8[0] + qa.y * (float)kv8[1] +
               qa.z * (float)kv8[2] + qa.w * (float)kv8[3] +
               qc.x * (float)kv8[4] + qc.y * (float)kv8[5] +
               qc.z * (float)kv8[6] + qc.w * (float)kv8[7];
    }
#pragma unroll
    for (int o = 32; o; o >>= 1) sum += __shfl_down(sum, o);
    if (lane == 0) logits[gw] = sum * 0.03125f;     // 1/sqrt(1024)
}

// ============================================================================
// K7: softmax over 4096 per batch (one block per batch)
// ============================================================================
__global__ void softmax_k(const float* __restrict__ logits,
                          float* __restrict__ wts) {
    int b = blockIdx.x, tid = threadIdx.x;
    const float* l = logits + b * SS;
    __shared__ float redm[4], reds[4];
    float m = -1e30f;
    for (int i = tid; i < SS; i += 256) m = fmaxf(m, l[i]);
#pragma unroll
    for (int o = 32; o; o >>= 1) m = fmaxf(m, __shfl_down(m, o));
    if ((tid & 63) == 0) redm[tid >> 6] = m;
    __syncthreads();
    m = fmaxf(fmaxf(redm[0], redm[1]), fmaxf(redm[2], redm[3]));
    float s = 0.0f;
    for (int i = tid; i < SS; i += 256) s += expf(l[i] - m);
#pragma unroll
    for (int o = 32; o; o >>= 1) s += __shfl_down(s, o);
    if ((tid & 63) == 0) reds[tid >> 6] = s;
    __syncthreads();
    s = reds[0] + reds[1] + reds[2] + reds[3];
    float inv = 1.0f / s;
    for (int i = tid; i < SS; i += 256) wts[b * SS + i] = expf(l[i] - m) * inv;
}

// ============================================================================
// K8: h_final[b] += sum_t wts[b][t] * V[b,t]   (V = KV cols [1024,2048))
// grid: b(4) x dchunk(4) x tseg(16) = 256 blocks, atomicAdd fp32
// ============================================================================
__global__ void attn_av(const bf16* __restrict__ KV,
                        const float* __restrict__ wts,
                        float* __restrict__ h_final) {
    int bx = blockIdx.x;
    int b = bx >> 6, dc = (bx >> 4) & 3, ts = bx & 15;
    int tid = threadIdx.x;
    int d = dc * 256 + tid;
    const bf16* Vb = KV + (size_t)(b * SS + ts * 256) * NKV + EMBED + d;
    const float* wb = wts + b * SS + ts * 256;
    float acc = 0.0f;
#pragma unroll 8
    for (int j = 0; j < 256; ++j)
        acc += wb[j] * (float)Vb[(size_t)j * NKV];
    atomicAdd(h_final + b * EMBED + d, acc);
}

// ============================================================================
// K9: out[b] += h_final[b] @ out_w   (fp32, HBM-bound on out_w 128MB)
// grid: x = 125 j-chunks of 256, y = 4 d-segments of 256; atomicAdd
// ============================================================================
__global__ void out_gemm(const float* __restrict__ h_final,
                         const float* __restrict__ out_w,
                         float* __restrict__ out) {
    __shared__ float hs[BB * 256];
    int tid = threadIdx.x;
    int j = blockIdx.x * 256 + tid;             // 125*256 = 32000 exactly
    int d0 = blockIdx.y * 256;
    for (int i = tid; i < BB * 256; i += 256)
        hs[i] = h_final[(i >> 8) * EMBED + d0 + (i & 255)];
    __syncthreads();
    float a0 = 0, a1 = 0, a2 = 0, a3 = 0;
#pragma unroll 4
    for (int dd = 0; dd < 256; ++dd) {
        float wv = out_w[(size_t)(d0 + dd) * VOCAB + j];
        a0 += hs[dd] * wv; a1 += hs[256 + dd] * wv;
        a2 += hs[512 + dd] * wv; a3 += hs[768 + dd] * wv;
    }
    atomicAdd(out + j, a0);
    atomicAdd(out + VOCAB + j, a1);
    atomicAdd(out + 2 * VOCAB + j, a2);
    atomicAdd(out + 3 * VOCAB + j, a3);
}

// ============================================================================
extern "C" void kernel_launch(void* const* d_in, const int* in_sizes, int n_in,
                              void* d_out, int out_size, void* d_ws, size_t ws_size,
                              hipStream_t stream) {
    const int*   x      = (const int*)d_in[0];
    const float* embed  = (const float*)d_in[1];
    const float* qkv_w  = (const float*)d_in[2];
    const float* qkv_b  = (const float*)d_in[3];
    const float* out_w  = (const float*)d_in[4];
    const float* out_b  = (const float*)d_in[5];
    float* out = (float*)d_out;

    char* ws = (char*)d_ws;
    // workspace layout (all 16B-aligned):
    bf16*  h       = (bf16*)(ws);                         // 32 MB
    bf16*  KV      = (bf16*)(ws + 33554432);              // 64 MB
    bf16*  WkvT    = (bf16*)(ws + 100663296);             // 4 MB
    float* h_last  = (float*)(ws + 104857600);            // 16 KB
    float* h_final = (float*)(ws + 104873984);            // 16 KB
    float* q       = (float*)(ws + 104890368);            // 16 KB
    float* logits  = (float*)(ws + 104906752);            // 64 KB
    float* wts     = (float*)(ws + 104972288);            // 64 KB
    // total: ~100.2 MB

    gather_embed<<<NTOK, 256, 0, stream>>>(x, embed, h, h_last, h_final);
    init_qout<<<(BB * VOCAB + BB * EMBED + 255) / 256, 256, 0, stream>>>(
        qkv_b, out_b, q, out);
    wkvt_transpose<<<dim3(64, 32), 256, 0, stream>>>(qkv_w, WkvT);
    q_gemm<<<dim3(4, 4), 256, 0, stream>>>(h_last, qkv_w, q);
    gemm_kv<<<dim3(NTOK / 128, NKV / 128), 256, 0, stream>>>(
        h, WkvT, qkv_b + EMBED, KV);
    attn_logits<<<SS, 256, 0, stream>>>(KV, q, logits);
    softmax_k<<<BB, 256, 0, stream>>>(logits, wts);
    attn_av<<<256, 256, 0, stream>>>(KV, wts, h_final);
    out_gemm<<<dim3(VOCAB / 256, 4), 256, 0, stream>>>(h_final, out_w, out);
}

// Round 2
// 397.315 us; speedup vs baseline: 1.0909x; 1.0909x over previous
//
#include <hip/hip_runtime.h>
#include <hip/hip_bf16.h>

typedef __bf16 bf16;
typedef __bf16 bf16x4 __attribute__((ext_vector_type(4)));
typedef __bf16 bf16x8 __attribute__((ext_vector_type(8)));
typedef float floatx4 __attribute__((ext_vector_type(4)));

#define EMBED 1024
#define VOCAB 32000
#define BB    4
#define SS    4096
#define NTOK  (BB * SS)   // 16384
#define NKV   2048        // K and V concatenated
#define NSEG  16          // d-segments for partial-buffer GEMMs

// ---- async global->LDS, 16B per lane (lane-contiguous LDS dest required) ----
__device__ __forceinline__ void async_copy16(void* lds, const void* g) {
    __builtin_amdgcn_global_load_lds(
        (const __attribute__((address_space(1))) unsigned int*)g,
        (__attribute__((address_space(3))) unsigned int*)lds, 16, 0, 0);
}

// ============================================================================
// K1: gather h = embed[x] -> bf16; stash last token per batch (fp32) as both
// q-input (h_last) and residual init (h_final).
// ============================================================================
__global__ void gather_embed(const int* __restrict__ x,
                             const float* __restrict__ embed,
                             bf16* __restrict__ h,
                             float* __restrict__ h_last,
                             float* __restrict__ h_final) {
    int t = blockIdx.x;            // 16384 tokens
    int tid = threadIdx.x;         // 256
    int row = x[t];                // broadcast scalar load
    const float4* src = (const float4*)(embed + (size_t)row * EMBED);
    float4 v = src[tid];
    bf16x4 o; o.x = (bf16)v.x; o.y = (bf16)v.y; o.z = (bf16)v.z; o.w = (bf16)v.w;
    *(bf16x4*)(h + (size_t)t * EMBED + tid * 4) = o;
    if ((t & (SS - 1)) == SS - 1) {
        int b = t >> 12;
        *(float4*)(h_last  + b * EMBED + tid * 4) = v;
        *(float4*)(h_final + b * EMBED + tid * 4) = v;
    }
}

// ============================================================================
// K2: transpose+convert qkv_w[:, 1024:3072] -> WkvT[n][d] bf16 (2048 x 1024)
// ============================================================================
__global__ void wkvt_transpose(const float* __restrict__ qkv_w,
                               bf16* __restrict__ WkvT) {
    __shared__ float T[32][33];
    int n0 = blockIdx.x * 32, d0 = blockIdx.y * 32;
    int tid = threadIdx.x;
    int c = tid & 31, r = tid >> 5;
#pragma unroll
    for (int i = 0; i < 4; ++i) {
        int d = r + i * 8;
        T[c][d] = qkv_w[(size_t)(d0 + d) * (3 * EMBED) + EMBED + n0 + c];
    }
    __syncthreads();
#pragma unroll
    for (int i = 0; i < 4; ++i) {
        int n = r + i * 8;
        WkvT[(size_t)(n0 + n) * EMBED + d0 + c] = (bf16)T[n][c];
    }
}

// ============================================================================
// K3: q partials. qpart[seg][b][j] = sum_{d in seg} h_last[b][d]*qkv_w[d][j]
// grid = NSEG blocks (d-seg of 64), thread covers 4 cols via float4.
// ============================================================================
__global__ void q_gemm(const float* __restrict__ h_last,
                       const float* __restrict__ qkv_w,
                       float* __restrict__ qpart) {
    __shared__ float hs[BB * 64];
    int tid = threadIdx.x;
    int seg = blockIdx.x, d0 = seg * 64;
    hs[tid] = h_last[(tid >> 6) * EMBED + d0 + (tid & 63)];
    __syncthreads();
    int j0 = tid * 4;                           // 0..1023
    floatx4 acc[BB];
#pragma unroll
    for (int b = 0; b < BB; ++b) acc[b] = (floatx4)0.0f;
#pragma unroll 4
    for (int dd = 0; dd < 64; ++dd) {
        float4 w = *(const float4*)(qkv_w + (size_t)(d0 + dd) * (3 * EMBED) + j0);
#pragma unroll
        for (int b = 0; b < BB; ++b) {
            float hv = hs[b * 64 + dd];
            acc[b][0] += hv * w.x; acc[b][1] += hv * w.y;
            acc[b][2] += hv * w.z; acc[b][3] += hv * w.w;
        }
    }
#pragma unroll
    for (int b = 0; b < BB; ++b)
        *(floatx4*)(qpart + ((size_t)seg * BB + b) * EMBED + j0) = acc[b];
}

// K3b: q[b][d] = qkv_b[d] + sum_seg qpart[seg][b][d]
__global__ void q_reduce(const float* __restrict__ qpart,
                         const float* __restrict__ qkv_b,
                         float* __restrict__ q) {
    int k = blockIdx.x * 256 + threadIdx.x;     // 4096
    int b = k >> 10, d = k & (EMBED - 1);
    float s = qkv_b[d];
#pragma unroll
    for (int sg = 0; sg < NSEG; ++sg) s += qpart[((size_t)sg * BB + b) * EMBED + d];
    q[k] = s;
}

// ============================================================================
// K4: the big GEMM (unchanged). KV = h @ WkvT^T + bias, bf16 MFMA 16x16x32.
// ============================================================================
__global__ __launch_bounds__(256, 2) void gemm_kv(
    const bf16* __restrict__ A,    // 16384 x 1024 row-major
    const bf16* __restrict__ BT,   // 2048 x 1024
    const float* __restrict__ bias,// 2048
    bf16* __restrict__ C) {        // 16384 x 2048
    __shared__ bf16 As[128 * 32];
    __shared__ bf16 Bs[128 * 32];
    const int K = EMBED;
    int tid = threadIdx.x;
    int wave = tid >> 6, lane = tid & 63;
    int wm = wave >> 1, wn = wave & 1;
    int quad = lane >> 4, l16 = lane & 15;

    floatx4 acc[4][4];
#pragma unroll
    for (int a = 0; a < 4; ++a)
#pragma unroll
        for (int b = 0; b < 4; ++b) acc[a][b] = (floatx4)0.0f;

    const bf16* Abase = A + (size_t)blockIdx.x * 128 * K;
    const bf16* Bbase = BT + (size_t)blockIdx.y * 128 * K;

    for (int k0 = 0; k0 < K; k0 += 32) {
        __syncthreads();
#pragma unroll
        for (int i = 0; i < 2; ++i) {
            int c = wave * 128 + i * 64 + lane;
            int row = c >> 2, ko = (c & 3) * 8;
            async_copy16(As + c * 8, Abase + (size_t)row * K + k0 + ko);
            async_copy16(Bs + c * 8, Bbase + (size_t)row * K + k0 + ko);
        }
        __syncthreads();
        bf16x8 af[4], bfr[4];
#pragma unroll
        for (int mt = 0; mt < 4; ++mt)
            af[mt] = *(const bf16x8*)(As + (wm * 64 + mt * 16 + l16) * 32 + quad * 8);
#pragma unroll
        for (int nt = 0; nt < 4; ++nt)
            bfr[nt] = *(const bf16x8*)(Bs + (wn * 64 + nt * 16 + l16) * 32 + quad * 8);
#pragma unroll
        for (int mt = 0; mt < 4; ++mt)
#pragma unroll
            for (int nt = 0; nt < 4; ++nt)
                acc[mt][nt] = __builtin_amdgcn_mfma_f32_16x16x32_bf16(
                    af[mt], bfr[nt], acc[mt][nt], 0, 0, 0);
    }

    int crow0 = blockIdx.x * 128 + wm * 64;
    int ccol0 = blockIdx.y * 128 + wn * 64;
#pragma unroll
    for (int mt = 0; mt < 4; ++mt)
#pragma unroll
        for (int nt = 0; nt < 4; ++nt) {
            int col = ccol0 + nt * 16 + l16;
            float bs = bias[col];
#pragma unroll
            for (int r = 0; r < 4; ++r) {
                int row = crow0 + mt * 16 + quad * 4 + r;
                C[(size_t)row * NKV + col] = (bf16)(acc[mt][nt][r] + bs);
            }
        }
}

// ============================================================================
// K5: logits[b][t] = (q[b] . K[b,t]) / 32 — one wave per t; q staged in LDS.
// ============================================================================
__global__ void attn_logits(const bf16* __restrict__ KV,
                            const float* __restrict__ q,
                            float* __restrict__ logits) {
    __shared__ float qs[EMBED];
    int b = blockIdx.x >> 10;                   // 1024 blocks per batch
    int t = (blockIdx.x & 1023) * 4 + (threadIdx.x >> 6);
    int lane = threadIdx.x & 63;
    *(float4*)(qs + threadIdx.x * 4) = *(const float4*)(q + b * EMBED + threadIdx.x * 4);
    __syncthreads();
    const bf16* Krow = KV + (size_t)(b * SS + t) * NKV;
    float sum = 0.0f;
#pragma unroll
    for (int i = 0; i < 2; ++i) {
        int d0 = i * 512 + lane * 8;
        bf16x8 kv8 = *(const bf16x8*)(Krow + d0);
        float4 qa = *(const float4*)(qs + d0);
        float4 qc = *(const float4*)(qs + d0 + 4);
        sum += qa.x * (float)kv8[0] + qa.y * (float)kv8[1] +
               qa.z * (float)kv8[2] + qa.w * (float)kv8[3] +
               qc.x * (float)kv8[4] + qc.y * (float)kv8[5] +
               qc.z * (float)kv8[6] + qc.w * (float)kv8[7];
    }
#pragma unroll
    for (int o = 32; o; o >>= 1) sum += __shfl_down(sum, o);
    if (lane == 0) logits[b * SS + t] = sum * 0.03125f;
}

// ============================================================================
// K6: softmax over 4096 per batch — one 1024-thread block per batch,
// exp computed once in registers.
// ============================================================================
__global__ void softmax_k(const float* __restrict__ logits,
                          float* __restrict__ wts) {
    int b = blockIdx.x, tid = threadIdx.x;      // 1024 threads
    __shared__ float redm[16], reds[16];
    const float* l = logits + b * SS;
    float x0 = l[tid], x1 = l[tid + 1024], x2 = l[tid + 2048], x3 = l[tid + 3072];
    float m = fmaxf(fmaxf(x0, x1), fmaxf(x2, x3));
#pragma unroll
    for (int o = 32; o; o >>= 1) m = fmaxf(m, __shfl_down(m, o));
    if ((tid & 63) == 0) redm[tid >> 6] = m;
    __syncthreads();
    float M = redm[0];
#pragma unroll
    for (int i = 1; i < 16; ++i) M = fmaxf(M, redm[i]);
    float e0 = expf(x0 - M), e1 = expf(x1 - M), e2 = expf(x2 - M), e3 = expf(x3 - M);
    float s = e0 + e1 + e2 + e3;
#pragma unroll
    for (int o = 32; o; o >>= 1) s += __shfl_down(s, o);
    if ((tid & 63) == 0) reds[tid >> 6] = s;
    __syncthreads();
    float S = 0.0f;
#pragma unroll
    for (int i = 0; i < 16; ++i) S += reds[i];
    float inv = 1.0f / S;
    float* w = wts + b * SS;
    w[tid] = e0 * inv; w[tid + 1024] = e1 * inv;
    w[tid + 2048] = e2 * inv; w[tid + 3072] = e3 * inv;
}

// ============================================================================
// K7: h_final[b] += sum_t wts[b][t] * V[b,t]
// grid: b(4) x tseg(64 of 64 t) = 256 blocks; thread covers 4 d via bf16x4.
// ============================================================================
__global__ void attn_av(const bf16* __restrict__ KV,
                        const float* __restrict__ wts,
                        float* __restrict__ h_final) {
    int b = blockIdx.x >> 6, ts = blockIdx.x & 63;
    int tid = threadIdx.x;
    __shared__ float wsh[64];
    if (tid < 64) wsh[tid] = wts[b * SS + ts * 64 + tid];
    __syncthreads();
    int d = tid * 4;
    const bf16* Vb = KV + (size_t)(b * SS + ts * 64) * NKV + EMBED + d;
    float a0 = 0, a1 = 0, a2 = 0, a3 = 0;
#pragma unroll 4
    for (int j = 0; j < 64; ++j) {
        bf16x4 v = *(const bf16x4*)(Vb + (size_t)j * NKV);
        float w = wsh[j];
        a0 += w * (float)v.x; a1 += w * (float)v.y;
        a2 += w * (float)v.z; a3 += w * (float)v.w;
    }
    atomicAdd(h_final + b * EMBED + d + 0, a0);
    atomicAdd(h_final + b * EMBED + d + 1, a1);
    atomicAdd(h_final + b * EMBED + d + 2, a2);
    atomicAdd(h_final + b * EMBED + d + 3, a3);
}

// ============================================================================
// K8: out partials. opart[seg][b][j] = sum_{d in seg} h_final[b][d]*out_w[d][j]
// grid: x = 32 j-chunks of 1024 (last partial), y = NSEG d-segs of 64.
// float4 per thread; atomic-free.
// ============================================================================
__global__ void out_gemm(const float* __restrict__ h_final,
                         const float* __restrict__ out_w,
                         float* __restrict__ opart) {
    __shared__ float hs[BB * 64];
    int tid = threadIdx.x;
    int seg = blockIdx.y, d0 = seg * 64;
    hs[tid] = h_final[(tid >> 6) * EMBED + d0 + (tid & 63)];
    __syncthreads();
    int j0 = blockIdx.x * 1024 + tid * 4;
    if (j0 >= VOCAB) return;                    // tail block: tid >= 64 idle
    floatx4 acc[BB];
#pragma unroll
    for (int b = 0; b < BB; ++b) acc[b] = (floatx4)0.0f;
#pragma unroll 4
    for (int dd = 0; dd < 64; ++dd) {
        float4 w = *(const float4*)(out_w + (size_t)(d0 + dd) * VOCAB + j0);
#pragma unroll
        for (int b = 0; b < BB; ++b) {
            float hv = hs[b * 64 + dd];
            acc[b][0] += hv * w.x; acc[b][1] += hv * w.y;
            acc[b][2] += hv * w.z; acc[b][3] += hv * w.w;
        }
    }
#pragma unroll
    for (int b = 0; b < BB; ++b)
        *(floatx4*)(opart + ((size_t)seg * BB + b) * VOCAB + j0) = acc[b];
}

// K8b: out[b][j] = out_b[j] + sum_seg opart[seg][b][j]
__global__ void out_reduce(const float* __restrict__ opart,
                           const float* __restrict__ out_b,
                           float* __restrict__ out) {
    int i = blockIdx.x * 256 + threadIdx.x;     // 128000
    if (i >= BB * VOCAB) return;
    int b = i / VOCAB, j = i - b * VOCAB;
    float s = out_b[j];
#pragma unroll
    for (int sg = 0; sg < NSEG; ++sg) s += opart[((size_t)sg * BB + b) * VOCAB + j];
    out[i] = s;
}

// ============================================================================
extern "C" void kernel_launch(void* const* d_in, const int* in_sizes, int n_in,
                              void* d_out, int out_size, void* d_ws, size_t ws_size,
                              hipStream_t stream) {
    const int*   x      = (const int*)d_in[0];
    const float* embed  = (const float*)d_in[1];
    const float* qkv_w  = (const float*)d_in[2];
    const float* qkv_b  = (const float*)d_in[3];
    const float* out_w  = (const float*)d_in[4];
    const float* out_b  = (const float*)d_in[5];
    float* out = (float*)d_out;

    char* ws = (char*)d_ws;
    bf16*  h       = (bf16*)(ws);                         // 32 MiB
    float* opart   = (float*)(ws);                        // 8 MiB, overlays h (h dead after gemm_kv)
    bf16*  KV      = (bf16*)(ws + 33554432);              // 64 MiB
    bf16*  WkvT    = (bf16*)(ws + 100663296);             // 4 MiB
    float* h_last  = (float*)(ws + 104857600);            // 16 KiB
    float* h_final = (float*)(ws + 104873984);            // 16 KiB
    float* q       = (float*)(ws + 104890368);            // 16 KiB
    float* logits  = (float*)(ws + 104906752);            // 64 KiB
    float* wts     = (float*)(ws + 104972288);            // 64 KiB
    float* qpart   = (float*)(ws + 105037824);            // 256 KiB

    gather_embed<<<NTOK, 256, 0, stream>>>(x, embed, h, h_last, h_final);
    wkvt_transpose<<<dim3(64, 32), 256, 0, stream>>>(qkv_w, WkvT);
    q_gemm<<<NSEG, 256, 0, stream>>>(h_last, qkv_w, qpart);
    q_reduce<<<16, 256, 0, stream>>>(qpart, qkv_b, q);
    gemm_kv<<<dim3(NTOK / 128, NKV / 128), 256, 0, stream>>>(
        h, WkvT, qkv_b + EMBED, KV);
    attn_logits<<<SS, 256, 0, stream>>>(KV, q, logits);
    softmax_k<<<BB, 1024, 0, stream>>>(logits, wts);
    attn_av<<<256, 256, 0, stream>>>(KV, wts, h_final);
    out_gemm<<<dim3(32, NSEG), 256, 0, stream>>>(h_final, out_w, opart);
    out_reduce<<<(BB * VOCAB + 255) / 256, 256, 0, stream>>>(opart, out_b, out);
}